// Round 3
// baseline (612.105 us; speedup 1.0000x reference)
//
#include <hip/hip_runtime.h>
#include <hip/hip_bf16.h>
#include <stdint.h>

#define E_      8
#define T_      8192
#define DIN_    2048
#define DOUT_   2048
#define BM_     128
#define BN_     128
#define BK_     32
#define MT_MAX_ 72            // T/BM + E upper bound on row tiles
#define NT_     (DOUT_/BN_)   // 16
#define KSTEPS_ (DIN_/BK_)    // 64

// Exact power-of-2 pre-scales so the f16 lo-parts stay in normal range
// (guards against possible MFMA denormal-input flush-to-zero):
//   A' = A * 2^10, B' = B * 2^14, out = acc * 2^-24.
#define ASCALE_ 1024.0f
#define BSCALE_ 16384.0f
#define OSCALE_ (1.0f / 16777216.0f)

typedef _Float16 f16x8 __attribute__((ext_vector_type(8)));
typedef float    f32x4 __attribute__((ext_vector_type(4)));

// ---- workspace layout (bytes) ----
#define WS_COUNTS 0            // 8 ints; cursors = next 8 ints (byte 32)
#define WS_OFFS   64           // 9 ints
#define WS_NTILES 100          // 1 int
#define WS_TILES  128          // MT_MAX_*3 ints {expert,row_start,row_end}
#define WS_PERM   4096         // T_ ints
#define WS_AH     65536ull
#define SZ_A      ((size_t)T_*DIN_*2)                // 32 MiB
#define SZ_B      ((size_t)E_*(size_t)DIN_*DOUT_*2)  // 64 MiB
#define WS_AL     (WS_AH + SZ_A)
#define WS_BH     (WS_AL + SZ_A)
#define WS_BL     (WS_BH + SZ_B)
#define WS_END    (WS_BL + SZ_B)

__device__ __forceinline__ void gload_lds16(const void* g, void* l) {
  __builtin_amdgcn_global_load_lds(
      (const __attribute__((address_space(1))) void*)g,
      (__attribute__((address_space(3))) void*)l, 16, 0, 0);
}

// ---------- setup kernels ----------
__global__ void k_zero16(int* p) {
  if (threadIdx.x < 16) p[threadIdx.x] = 0;   // counts[8] + cursors[8]
}

__global__ void k_histo(const int* __restrict__ ids, int* __restrict__ counts) {
  __shared__ int h[E_];
  if (threadIdx.x < E_) h[threadIdx.x] = 0;
  __syncthreads();
  int t = blockIdx.x * 256 + threadIdx.x;
  if (t < T_) atomicAdd(&h[ids[t]], 1);
  __syncthreads();
  if (threadIdx.x < E_) atomicAdd(&counts[threadIdx.x], h[threadIdx.x]);
}

__global__ void k_scan_tiles(const int* __restrict__ counts, int* __restrict__ offs,
                             int* __restrict__ ntiles, int* __restrict__ tiles) {
  if (threadIdx.x == 0 && blockIdx.x == 0) {
    int acc = 0;
    for (int e = 0; e < E_; e++) { offs[e] = acc; acc += counts[e]; }
    offs[E_] = acc;
    int nt = 0;
    for (int e = 0; e < E_; e++) {
      int s = offs[e], ee = offs[e + 1];
      for (int r = s; r < ee; r += BM_) {
        tiles[nt*3+0] = e; tiles[nt*3+1] = r; tiles[nt*3+2] = ee; nt++;
      }
    }
    *ntiles = nt;
  }
}

__global__ void k_scatter(const int* __restrict__ ids, const int* __restrict__ offs,
                          int* __restrict__ curs, int* __restrict__ perm) {
  int t = blockIdx.x * 256 + threadIdx.x;
  if (t >= T_) return;
  int e = ids[t];
  int pos = offs[e] + atomicAdd(&curs[e], 1);
  perm[pos] = t;
}

// ---------- conversion: tokens -> gathered (sorted) scaled f16 hi/lo ----------
__global__ __launch_bounds__(256) void k_conv_tokens(
    const float* __restrict__ tokens, const int* __restrict__ perm,
    _Float16* __restrict__ Ah, _Float16* __restrict__ Al) {
  int r = blockIdx.x;                 // sorted row
  int tok = perm[r];
  const float4* src = (const float4*)(tokens + (size_t)tok * DIN_);
  int i = threadIdx.x;                // 256 threads * 8 elems = 2048
  float4 x0 = src[i*2], x1 = src[i*2+1];
  float xs[8] = {x0.x, x0.y, x0.z, x0.w, x1.x, x1.y, x1.z, x1.w};
  f16x8 h, l;
#pragma unroll
  for (int j = 0; j < 8; j++) {
    float x = xs[j] * ASCALE_;
    _Float16 hi = (_Float16)x;
    h[j] = hi;
    l[j] = (_Float16)(x - (float)hi);
  }
  *(f16x8*)(Ah + (size_t)r * DIN_ + i*8) = h;
  *(f16x8*)(Al + (size_t)r * DIN_ + i*8) = l;
}

// ---------- conversion: weights [e][k][n] -> transposed [e][n][k] scaled f16 hi/lo ----------
__global__ __launch_bounds__(256) void k_conv_weights(
    const float* __restrict__ W, _Float16* __restrict__ Bh, _Float16* __restrict__ Bl) {
  __shared__ float t[64][72];         // 72-float stride: 16B-aligned rows, bank-spread
  int b  = blockIdx.x;                // E_ * 32 * 32 = 8192
  int e  = b >> 10;
  int kt = (b >> 5) & 31;
  int nt = b & 31;
  const float* src = W + (size_t)e * DIN_ * DOUT_ + (size_t)(kt*64) * DOUT_ + nt*64;
  int tid = threadIdx.x;
#pragma unroll
  for (int rr = 0; rr < 4; rr++) {
    int row = rr*16 + (tid >> 4);     // k-local
    float4 v = *(const float4*)(src + (size_t)row * DOUT_ + (tid & 15) * 4);
    *(float4*)&t[row][(tid & 15) * 4] = v;
  }
  __syncthreads();
  int n  = tid >> 2;                  // 0..63 (n-local)
  int kc = (tid & 3) * 16;            // k-chunk
  f16x8 h0, h1, l0, l1;
#pragma unroll
  for (int kk = 0; kk < 8; kk++) {
    float x = t[kc + kk][n] * BSCALE_;
    _Float16 hi = (_Float16)x;
    h0[kk] = hi; l0[kk] = (_Float16)(x - (float)hi);
  }
#pragma unroll
  for (int kk = 0; kk < 8; kk++) {
    float x = t[kc + 8 + kk][n] * BSCALE_;
    _Float16 hi = (_Float16)x;
    h1[kk] = hi; l1[kk] = (_Float16)(x - (float)hi);
  }
  size_t dst = (size_t)e * DIN_ * DOUT_ + (size_t)(nt*64 + n) * DIN_ + (kt*64 + kc);
  *(f16x8*)(Bh + dst)     = h0;  *(f16x8*)(Bh + dst + 8) = h1;
  *(f16x8*)(Bl + dst)     = l0;  *(f16x8*)(Bl + dst + 8) = l1;
}

// ---------- main grouped GEMM: 128x128x32, 4 waves (2x2), 4x4 frags/wave ----------
// LDS: [Ah 8K][Al 8K][Bh 8K][Bl 8K], all [128 rows][32 k] f16,
// XOR-swizzled: 16B slot c stored at c ^ ((row>>1)&3).
// Grid is 1D (1152 = 8 XCDs * 144). Bijective XCD swizzle (nwg%8==0):
// XCD x owns n-columns {2x, 2x+1}, traversed in 2(mt)x2(nt) supertiles so
// B-panels get ~9 L2-resident reuses and A-tiles 2 adjacent uses (<4MiB L2).
__global__ __launch_bounds__(256) void k_moe_gemm(
    const _Float16* __restrict__ Ah, const _Float16* __restrict__ Al,
    const _Float16* __restrict__ Bh, const _Float16* __restrict__ Bl,
    const int* __restrict__ tiles, const int* __restrict__ ntl,
    const int* __restrict__ perm, float* __restrict__ out) {
  __shared__ char lds[32768];
  int lin = blockIdx.x;               // dispatch order; XCD = lin & 7 (heuristic)
  int xcd = lin & 7;
  int j   = lin >> 3;                 // 0..143 within this XCD
  int mt  = (j >> 2) * 2 + (j & 1);   // 0..71
  int nt  = xcd * 2 + ((j >> 1) & 1); // 0..15, fixed pair per XCD
  if (mt >= *ntl) return;
  int e = tiles[mt*3+0], row_start = tiles[mt*3+1], row_end = tiles[mt*3+2];
  int tid = threadIdx.x, lane = tid & 63, wave = tid >> 6;
  int wr = wave >> 1, wn = wave & 1;        // 2x2 wave grid, 64x64 per wave
  int n0 = nt * BN_;

  // per-thread global source pointers for the 8 staging calls (k advances by BK_)
  const _Float16* gsrc[8];
#pragma unroll
  for (int c = 0; c < 8; c++) {
    int tilei = c >> 1;
    int q   = ((c & 1) << 12) + tid * 16;   // byte pos within 8 KiB tile
    int row = q >> 6;                        // 64 B per row
    int slot = (q >> 4) & 3;
    int sg = slot ^ ((row >> 1) & 3);        // pre-swizzled source slot
    if (tilei < 2) {
      int rg = row_start + row; if (rg > T_ - 1) rg = T_ - 1;   // clamp pad rows
      const _Float16* base = (tilei == 0) ? Ah : Al;
      gsrc[c] = base + (size_t)rg * DIN_ + sg * 8;
    } else {
      int ng = n0 + row;
      const _Float16* base = (tilei == 2) ? Bh : Bl;
      gsrc[c] = base + (size_t)e * DIN_ * DOUT_ + (size_t)ng * DIN_ + sg * 8;
    }
  }

  // hoisted swizzled LDS read offsets (constant over K)
  int rsel = lane & 15, ksel = lane >> 4;
  int aoff[4], boff[4];
#pragma unroll
  for (int m = 0; m < 4; m++) {
    int row = wr*64 + m*16 + rsel;
    aoff[m] = row*64 + ((ksel ^ ((row >> 1) & 3)) << 4);
  }
#pragma unroll
  for (int n = 0; n < 4; n++) {
    int row = wn*64 + n*16 + rsel;
    boff[n] = row*64 + ((ksel ^ ((row >> 1) & 3)) << 4);
  }

  f32x4 acc[4][4] = {};
  for (int k = 0; k < KSTEPS_; k++) {
#pragma unroll
    for (int c = 0; c < 8; c++) {
      gload_lds16(gsrc[c], lds + c*4096 + wave*1024);  // dest wave-uniform
      gsrc[c] += BK_;
    }
    __syncthreads();   // compiler emits vmcnt(0) drain before barrier

    f16x8 a_h[4], a_l[4], b_h[4], b_l[4];
#pragma unroll
    for (int m = 0; m < 4; m++) {
      a_h[m] = *(const f16x8*)(lds +         aoff[m]);
      a_l[m] = *(const f16x8*)(lds +  8192 + aoff[m]);
    }
#pragma unroll
    for (int n = 0; n < 4; n++) {
      b_h[n] = *(const f16x8*)(lds + 16384 + boff[n]);
      b_l[n] = *(const f16x8*)(lds + 24576 + boff[n]);
    }
#pragma unroll
    for (int m = 0; m < 4; m++)
#pragma unroll
      for (int n = 0; n < 4; n++) {
        acc[m][n] = __builtin_amdgcn_mfma_f32_16x16x32_f16(a_h[m], b_h[n], acc[m][n], 0, 0, 0);
        acc[m][n] = __builtin_amdgcn_mfma_f32_16x16x32_f16(a_h[m], b_l[n], acc[m][n], 0, 0, 0);
        acc[m][n] = __builtin_amdgcn_mfma_f32_16x16x32_f16(a_l[m], b_h[n], acc[m][n], 0, 0, 0);
      }
    __syncthreads();   // single-buffered LDS: protect against next stage
  }

  // epilogue: C/D layout col=lane&15, row=(lane>>4)*4+reg  [m89-verified]
  int colsel = lane & 15, rq = lane >> 4;
#pragma unroll
  for (int m = 0; m < 4; m++) {
#pragma unroll
    for (int r = 0; r < 4; r++) {
      int srow = row_start + wr*64 + m*16 + rq*4 + r;
      if (srow < row_end) {
        int tok = perm[srow];
        float* orow = out + (size_t)tok * DOUT_ + n0 + wn*64 + colsel;
#pragma unroll
        for (int n = 0; n < 4; n++) orow[n*16] = acc[m][n][r] * OSCALE_;
      }
    }
  }
}

// ---------- slow-but-correct fallback if ws is too small ----------
__global__ void k_naive(const float* __restrict__ tokens, const float* __restrict__ W,
                        const int* __restrict__ ids, float* __restrict__ out) {
  int t = blockIdx.x;
  int col = blockIdx.y * 256 + threadIdx.x;
  int e = ids[t];
  const float* a = tokens + (size_t)t * DIN_;
  const float* w = W + (size_t)e * DIN_ * DOUT_ + col;
  float s = 0.f;
  for (int k = 0; k < DIN_; k++) s += a[k] * w[(size_t)k * DOUT_];
  out[(size_t)t * DOUT_ + col] = s;
}

extern "C" void kernel_launch(void* const* d_in, const int* in_sizes, int n_in,
                              void* d_out, int out_size, void* d_ws, size_t ws_size,
                              hipStream_t stream) {
  const float* tokens = (const float*)d_in[0];
  const float* weight = (const float*)d_in[1];
  const int*   ids    = (const int*)d_in[2];
  float* out = (float*)d_out;
  char*  ws  = (char*)d_ws;

  if (ws_size < WS_END) {   // constant across calls -> graph-safe
    k_naive<<<dim3(T_, DOUT_/256), 256, 0, stream>>>(tokens, weight, ids, out);
    return;
  }

  int* counts = (int*)(ws + WS_COUNTS);
  int* curs   = counts + 8;
  int* offs   = (int*)(ws + WS_OFFS);
  int* ntl    = (int*)(ws + WS_NTILES);
  int* tiles  = (int*)(ws + WS_TILES);
  int* perm   = (int*)(ws + WS_PERM);
  _Float16* Ah = (_Float16*)(ws + WS_AH);
  _Float16* Al = (_Float16*)(ws + WS_AL);
  _Float16* Bh = (_Float16*)(ws + WS_BH);
  _Float16* Bl = (_Float16*)(ws + WS_BL);

  k_zero16<<<1, 64, 0, stream>>>(counts);
  k_histo<<<T_/256, 256, 0, stream>>>(ids, counts);
  k_scan_tiles<<<1, 64, 0, stream>>>(counts, offs, ntl, tiles);
  k_scatter<<<T_/256, 256, 0, stream>>>(ids, offs, curs, perm);
  k_conv_tokens<<<T_, 256, 0, stream>>>(tokens, perm, Ah, Al);
  k_conv_weights<<<E_*32*32, 256, 0, stream>>>(weight, Bh, Bl);
  k_moe_gemm<<<MT_MAX_*NT_, 256, 0, stream>>>(Ah, Al, Bh, Bl, tiles, ntl, perm, out);
}

// Round 5
// 521.049 us; speedup vs baseline: 1.1748x; 1.1748x over previous
//
#include <hip/hip_runtime.h>
#include <hip/hip_bf16.h>
#include <stdint.h>

#define E_      8
#define T_      8192
#define DIN_    2048
#define DOUT_   2048
#define BM_     128
#define BN_     128
#define BK_     32
#define MT_MAX_ 72            // T/BM + E upper bound on row tiles (max actual = 71)
#define NT_     (DOUT_/BN_)   // 16
#define KSTEPS_ (DIN_/BK_)    // 64

// Exact power-of-2 pre-scales so the f16 lo-parts stay in normal range
// (guards against possible MFMA denormal-input flush-to-zero):
//   A' = A * 2^10, B' = B * 2^14, out = acc * 2^-24.
#define ASCALE_ 1024.0f
#define BSCALE_ 16384.0f
#define OSCALE_ (1.0f / 16777216.0f)

typedef _Float16 f16x8 __attribute__((ext_vector_type(8)));
typedef float    f32x4 __attribute__((ext_vector_type(4)));

// ---- workspace layout (bytes) ----
#define WS_NTILES 100          // 1 int
#define WS_TILES  128          // MT_MAX_*3 ints {expert,row_start,row_end}
#define WS_PERM   4096         // T_ ints
#define WS_AH     65536ull
#define SZ_A      ((size_t)T_*DIN_*2)                // 32 MiB
#define SZ_B      ((size_t)E_*(size_t)DIN_*DOUT_*2)  // 64 MiB
#define WS_AL     (WS_AH + SZ_A)
#define WS_BH     (WS_AL + SZ_A)
#define WS_BL     (WS_BH + SZ_B)
#define WS_END    (WS_BL + SZ_B)

__device__ __forceinline__ void gload_lds16(const void* g, void* l) {
  __builtin_amdgcn_global_load_lds(
      (const __attribute__((address_space(1))) void*)g,
      (__attribute__((address_space(3))) void*)l, 16, 0, 0);
}

// ---------- routing: histogram + scan + tile list + scatter, ONE block ----------
// ids cached in LDS (32 KB); LDS atomics for histo & cursors (single CU, ~us).
__global__ __launch_bounds__(1024) void k_route(
    const int* __restrict__ ids, int* __restrict__ ntl,
    int* __restrict__ tiles, int* __restrict__ perm) {
  __shared__ int sid[T_];
  __shared__ int h[E_], offs[E_ + 1], cur[E_];
  int tid = threadIdx.x;
  if (tid < E_) { h[tid] = 0; cur[tid] = 0; }
  __syncthreads();
  for (int i = tid; i < T_; i += 1024) {
    int e = ids[i];
    sid[i] = e;
    atomicAdd(&h[e], 1);
  }
  __syncthreads();
  if (tid == 0) {
    int acc = 0;
    for (int e = 0; e < E_; e++) { offs[e] = acc; acc += h[e]; }
    offs[E_] = acc;
    int nt = 0;
    for (int e = 0; e < E_; e++) {
      int s = offs[e], ee = offs[e + 1];
      for (int r = s; r < ee; r += BM_) {
        tiles[nt*3+0] = e; tiles[nt*3+1] = r; tiles[nt*3+2] = ee; nt++;
      }
    }
    *ntl = nt;
  }
  __syncthreads();
  for (int i = tid; i < T_; i += 1024) {
    int e = sid[i];
    int pos = offs[e] + atomicAdd(&cur[e], 1);
    perm[pos] = i;
  }
}

// ---------- merged conversion ----------
// blocks [0, 8192):  weights [e][k][n] -> transposed [e][n][k] scaled f16 hi/lo.
//   stride-65 LDS: read bank=(8ch+j+n)%32, write bank=(r+c)%32 both 2-way (free,
//   m136). Stores 128B-contiguous per n-row (8 lanes x 16B).
// blocks [8192, 16384): tokens -> gathered (sorted) scaled f16 hi/lo.
__global__ __launch_bounds__(256) void k_conv(
    const float* __restrict__ W, const float* __restrict__ tokens,
    const int* __restrict__ perm,
    _Float16* __restrict__ Ah, _Float16* __restrict__ Al,
    _Float16* __restrict__ Bh, _Float16* __restrict__ Bl) {
  int tid = threadIdx.x;
  if (blockIdx.x < E_*32*32) {
    __shared__ float t[64][65];
    int b  = blockIdx.x;
    int e  = b >> 10;
    int kt = (b >> 5) & 31;
    int nt = b & 31;
    const float* src = W + (size_t)e * DIN_ * DOUT_ + (size_t)(kt*64) * DOUT_ + nt*64;
    int lr = tid >> 4;                  // 0..15
    int lc = (tid & 15) * 4;            // 0..60
#pragma unroll
    for (int p = 0; p < 4; p++) {
      int row = p*16 + lr;              // k-local
      float4 v = *(const float4*)(src + (size_t)row * DOUT_ + lc);
      t[row][lc+0] = v.x; t[row][lc+1] = v.y; t[row][lc+2] = v.z; t[row][lc+3] = v.w;
    }
    __syncthreads();
    int n8 = tid >> 3;                  // 0..31 (n-local)
    int ch = tid & 7;                   // 0..7 (k-chunk of 8)
#pragma unroll
    for (int p = 0; p < 2; p++) {
      int n = p*32 + n8;
      f16x8 h, l;
#pragma unroll
      for (int j = 0; j < 8; j++) {
        float x = t[ch*8 + j][n] * BSCALE_;
        _Float16 hi = (_Float16)x;
        h[j] = hi; l[j] = (_Float16)(x - (float)hi);
      }
      size_t dst = (size_t)e * DIN_ * DOUT_ + (size_t)(nt*64 + n) * DIN_ + kt*64 + ch*8;
      *(f16x8*)(Bh + dst) = h;
      *(f16x8*)(Bl + dst) = l;
    }
  } else {
    int r = blockIdx.x - E_*32*32;      // sorted row
    int tok = perm[r];
    const float4* src = (const float4*)(tokens + (size_t)tok * DIN_);
    float4 x0 = src[tid*2], x1 = src[tid*2+1];
    float xs[8] = {x0.x, x0.y, x0.z, x0.w, x1.x, x1.y, x1.z, x1.w};
    f16x8 h, l;
#pragma unroll
    for (int j = 0; j < 8; j++) {
      float x = xs[j] * ASCALE_;
      _Float16 hi = (_Float16)x;
      h[j] = hi;
      l[j] = (_Float16)(x - (float)hi);
    }
    *(f16x8*)(Ah + (size_t)r * DIN_ + tid*8) = h;
    *(f16x8*)(Al + (size_t)r * DIN_ + tid*8) = l;
  }
}

// ---------- main grouped GEMM: 128x128x32, 4 waves (2x2), 4x4 frags/wave ----------
// 2-phase double-buffered pipeline (T3-min): stage tile k+1 while computing
// tile k; ONE __syncthreads per K-step (its vmcnt/lgkmcnt drain provides both
// "prefetch landed" and "my ds_reads done before overwrite"). LDS 2x32KB.
// Per buffer: [Ah 8K][Al 8K][Bh 8K][Bl 8K], all [128 rows][32 k] f16,
// XOR-swizzled: 16B slot c stored at c ^ ((row>>1)&3).
// Grid 1D (1152 = 8 XCDs * 144), bijective XCD swizzle: XCD x owns n-columns
// {2x,2x+1} in 2(mt)x2(nt) supertiles -> B-panels ~9 L2-resident reuses.
__global__ __launch_bounds__(256) void k_moe_gemm(
    const _Float16* __restrict__ Ah, const _Float16* __restrict__ Al,
    const _Float16* __restrict__ Bh, const _Float16* __restrict__ Bl,
    const int* __restrict__ tiles, const int* __restrict__ ntl,
    const int* __restrict__ perm, float* __restrict__ out) {
  __shared__ char lds[65536];
  int lin = blockIdx.x;               // dispatch order; XCD = lin & 7 (heuristic)
  int xcd = lin & 7;
  int j   = lin >> 3;                 // 0..143 within this XCD
  int mt  = (j >> 2) * 2 + (j & 1);   // 0..71
  int nt  = xcd * 2 + ((j >> 1) & 1); // 0..15, fixed pair per XCD
  if (mt >= *ntl) return;
  int e = tiles[mt*3+0], row_start = tiles[mt*3+1], row_end = tiles[mt*3+2];
  int tid = threadIdx.x, lane = tid & 63, wave = tid >> 6;
  int wr = wave >> 1, wn = wave & 1;        // 2x2 wave grid, 64x64 per wave
  int n0 = nt * BN_;

  // per-thread global source pointers for the 8 staging calls (k advances by BK_)
  const _Float16* gsrc[8];
#pragma unroll
  for (int c = 0; c < 8; c++) {
    int tilei = c >> 1;
    int q   = ((c & 1) << 12) + tid * 16;   // byte pos within 8 KiB tile
    int row = q >> 6;                        // 64 B per row
    int slot = (q >> 4) & 3;
    int sg = slot ^ ((row >> 1) & 3);        // pre-swizzled source slot
    if (tilei < 2) {
      int rg = row_start + row; if (rg > T_ - 1) rg = T_ - 1;   // clamp pad rows
      const _Float16* base = (tilei == 0) ? Ah : Al;
      gsrc[c] = base + (size_t)rg * DIN_ + sg * 8;
    } else {
      int ng = n0 + row;
      const _Float16* base = (tilei == 2) ? Bh : Bl;
      gsrc[c] = base + (size_t)e * DIN_ * DOUT_ + (size_t)ng * DIN_ + sg * 8;
    }
  }

  // hoisted swizzled LDS read offsets (constant over K)
  int rsel = lane & 15, ksel = lane >> 4;
  int aoff[4], boff[4];
#pragma unroll
  for (int m = 0; m < 4; m++) {
    int row = wr*64 + m*16 + rsel;
    aoff[m] = row*64 + ((ksel ^ ((row >> 1) & 3)) << 4);
  }
#pragma unroll
  for (int n = 0; n < 4; n++) {
    int row = wn*64 + n*16 + rsel;
    boff[n] = row*64 + ((ksel ^ ((row >> 1) & 3)) << 4);
  }

  // prologue: stage K-step 0 into buffer 0
#pragma unroll
  for (int c = 0; c < 8; c++) {
    gload_lds16(gsrc[c], lds + c*4096 + wave*1024);
    gsrc[c] += BK_;
  }
  __syncthreads();

  f32x4 acc[4][4] = {};
  int cur = 0;
  for (int k = 0; k < KSTEPS_; k++) {
    // stage next K-step into the other buffer (overlaps with compute below)
    if (k + 1 < KSTEPS_) {
      int nb = (cur ^ 1) << 15;
#pragma unroll
      for (int c = 0; c < 8; c++) {
        gload_lds16(gsrc[c], lds + nb + c*4096 + wave*1024);
        gsrc[c] += BK_;
      }
    }

    const char* buf = lds + (cur << 15);
    f16x8 a_h[4], a_l[4], b_h[4], b_l[4];
#pragma unroll
    for (int m = 0; m < 4; m++) {
      a_h[m] = *(const f16x8*)(buf +         aoff[m]);
      a_l[m] = *(const f16x8*)(buf +  8192 + aoff[m]);
    }
#pragma unroll
    for (int n = 0; n < 4; n++) {
      b_h[n] = *(const f16x8*)(buf + 16384 + boff[n]);
      b_l[n] = *(const f16x8*)(buf + 24576 + boff[n]);
    }
    __builtin_amdgcn_s_setprio(1);
#pragma unroll
    for (int m = 0; m < 4; m++)
#pragma unroll
      for (int n = 0; n < 4; n++) {
        acc[m][n] = __builtin_amdgcn_mfma_f32_16x16x32_f16(a_h[m], b_h[n], acc[m][n], 0, 0, 0);
        acc[m][n] = __builtin_amdgcn_mfma_f32_16x16x32_f16(a_h[m], b_l[n], acc[m][n], 0, 0, 0);
        acc[m][n] = __builtin_amdgcn_mfma_f32_16x16x32_f16(a_l[m], b_h[n], acc[m][n], 0, 0, 0);
      }
    __builtin_amdgcn_s_setprio(0);
    // one barrier per K-step: drains vmcnt (prefetch landed in buf^1) and
    // lgkmcnt (our ds_reads of buf done before it's overwritten next iter)
    __syncthreads();
    cur ^= 1;
  }

  // epilogue: C/D layout col=lane&15, row=(lane>>4)*4+reg  [m89-verified]
  int colsel = lane & 15, rq = lane >> 4;
#pragma unroll
  for (int m = 0; m < 4; m++) {
#pragma unroll
    for (int r = 0; r < 4; r++) {
      int srow = row_start + wr*64 + m*16 + rq*4 + r;
      if (srow < row_end) {
        int tok = perm[srow];
        float* orow = out + (size_t)tok * DOUT_ + n0 + wn*64 + colsel;
#pragma unroll
        for (int n = 0; n < 4; n++) orow[n*16] = acc[m][n][r] * OSCALE_;
      }
    }
  }
}

// ---------- slow-but-correct fallback if ws is too small ----------
__global__ void k_naive(const float* __restrict__ tokens, const float* __restrict__ W,
                        const int* __restrict__ ids, float* __restrict__ out) {
  int t = blockIdx.x;
  int col = blockIdx.y * 256 + threadIdx.x;
  int e = ids[t];
  const float* a = tokens + (size_t)t * DIN_;
  const float* w = W + (size_t)e * DIN_ * DOUT_ + col;
  float s = 0.f;
  for (int k = 0; k < DIN_; k++) s += a[k] * w[(size_t)k * DOUT_];
  out[(size_t)t * DOUT_ + col] = s;
}

extern "C" void kernel_launch(void* const* d_in, const int* in_sizes, int n_in,
                              void* d_out, int out_size, void* d_ws, size_t ws_size,
                              hipStream_t stream) {
  const float* tokens = (const float*)d_in[0];
  const float* weight = (const float*)d_in[1];
  const int*   ids    = (const int*)d_in[2];
  float* out = (float*)d_out;
  char*  ws  = (char*)d_ws;

  if (ws_size < WS_END) {   // constant across calls -> graph-safe
    k_naive<<<dim3(T_, DOUT_/256), 256, 0, stream>>>(tokens, weight, ids, out);
    return;
  }

  int* ntl    = (int*)(ws + WS_NTILES);
  int* tiles  = (int*)(ws + WS_TILES);
  int* perm   = (int*)(ws + WS_PERM);
  _Float16* Ah = (_Float16*)(ws + WS_AH);
  _Float16* Al = (_Float16*)(ws + WS_AL);
  _Float16* Bh = (_Float16*)(ws + WS_BH);
  _Float16* Bl = (_Float16*)(ws + WS_BL);

  k_route<<<1, 1024, 0, stream>>>(ids, ntl, tiles, perm);
  k_conv<<<2*E_*32*32, 256, 0, stream>>>(weight, tokens, perm, Ah, Al, Bh, Bl);
  k_moe_gemm<<<MT_MAX_*NT_, 256, 0, stream>>>(Ah, Al, Bh, Bl, tiles, ntl, perm, out);
}

// Round 6
// 429.000 us; speedup vs baseline: 1.4268x; 1.2146x over previous
//
#include <hip/hip_runtime.h>
#include <hip/hip_bf16.h>
#include <stdint.h>

#define E_      8
#define T_      8192
#define DIN_    2048
#define DOUT_   2048
#define BM_     128
#define BN_     128
#define BK_     32
#define MT_MAX_ 72            // T/BM + E upper bound on row tiles (max actual = 71)
#define NT_     (DOUT_/BN_)   // 16
#define KSTEPS_ (DIN_/BK_)    // 64

// Split-f16 2-term scheme: A' = A*2^10 split into ah+al (exact to ~2^-22);
// B' = B*2^14 kept hi-only (bh).  out = (ah+al)*bh * 2^-24  ==  a * f16(w).
// Weight-rounding error absmax ~8e-4, ~20x below the reference's own 2^-6
// quantization error (measured absmax 0.015625, reference-dominated).
#define ASCALE_ 1024.0f
#define BSCALE_ 16384.0f
#define OSCALE_ (1.0f / 16777216.0f)

typedef _Float16 f16x8 __attribute__((ext_vector_type(8)));
typedef float    f32x4 __attribute__((ext_vector_type(4)));

// ---- workspace layout (bytes) ----
#define WS_NTILES 100          // 1 int
#define WS_TILES  128          // MT_MAX_*3 ints {expert,row_start,row_end}
#define WS_PERM   4096         // T_ ints
#define WS_AH     65536ull
#define SZ_A      ((size_t)T_*DIN_*2)                // 32 MiB
#define SZ_B      ((size_t)E_*(size_t)DIN_*DOUT_*2)  // 64 MiB
#define WS_AL     (WS_AH + SZ_A)
#define WS_BH     (WS_AL + SZ_A)
#define WS_END    (WS_BH + SZ_B)                     // ~128 MiB

__device__ __forceinline__ void gload_lds16(const void* g, void* l) {
  __builtin_amdgcn_global_load_lds(
      (const __attribute__((address_space(1))) void*)g,
      (__attribute__((address_space(3))) void*)l, 16, 0, 0);
}

// ---------- routing: histogram + scan + tile list + scatter, ONE block ----------
__global__ __launch_bounds__(1024) void k_route(
    const int* __restrict__ ids, int* __restrict__ ntl,
    int* __restrict__ tiles, int* __restrict__ perm) {
  __shared__ int sid[T_];
  __shared__ int h[E_], offs[E_ + 1], cur[E_];
  int tid = threadIdx.x;
  if (tid < E_) { h[tid] = 0; cur[tid] = 0; }
  __syncthreads();
  for (int i = tid; i < T_; i += 1024) {
    int e = ids[i];
    sid[i] = e;
    atomicAdd(&h[e], 1);
  }
  __syncthreads();
  if (tid == 0) {
    int acc = 0;
    for (int e = 0; e < E_; e++) { offs[e] = acc; acc += h[e]; }
    offs[E_] = acc;
    int nt = 0;
    for (int e = 0; e < E_; e++) {
      int s = offs[e], ee = offs[e + 1];
      for (int r = s; r < ee; r += BM_) {
        tiles[nt*3+0] = e; tiles[nt*3+1] = r; tiles[nt*3+2] = ee; nt++;
      }
    }
    *ntl = nt;
  }
  __syncthreads();
  for (int i = tid; i < T_; i += 1024) {
    int e = sid[i];
    int pos = offs[e] + atomicAdd(&cur[e], 1);
    perm[pos] = i;
  }
}

// ---------- merged conversion ----------
// blocks [0, 8192):  weights [e][k][n] -> transposed [e][n][k] scaled f16 (hi only).
//   stride-65 LDS: read/write banks both 2-way (free, m136). Stores 128B-contiguous.
// blocks [8192, 16384): tokens -> gathered (sorted) scaled f16 hi/lo.
__global__ __launch_bounds__(256) void k_conv(
    const float* __restrict__ W, const float* __restrict__ tokens,
    const int* __restrict__ perm,
    _Float16* __restrict__ Ah, _Float16* __restrict__ Al,
    _Float16* __restrict__ Bh) {
  int tid = threadIdx.x;
  if (blockIdx.x < E_*32*32) {
    __shared__ float t[64][65];
    int b  = blockIdx.x;
    int e  = b >> 10;
    int kt = (b >> 5) & 31;
    int nt = b & 31;
    const float* src = W + (size_t)e * DIN_ * DOUT_ + (size_t)(kt*64) * DOUT_ + nt*64;
    int lr = tid >> 4;                  // 0..15
    int lc = (tid & 15) * 4;            // 0..60
#pragma unroll
    for (int p = 0; p < 4; p++) {
      int row = p*16 + lr;              // k-local
      float4 v = *(const float4*)(src + (size_t)row * DOUT_ + lc);
      t[row][lc+0] = v.x; t[row][lc+1] = v.y; t[row][lc+2] = v.z; t[row][lc+3] = v.w;
    }
    __syncthreads();
    int n8 = tid >> 3;                  // 0..31 (n-local)
    int ch = tid & 7;                   // 0..7 (k-chunk of 8)
#pragma unroll
    for (int p = 0; p < 2; p++) {
      int n = p*32 + n8;
      f16x8 h;
#pragma unroll
      for (int j = 0; j < 8; j++)
        h[j] = (_Float16)(t[ch*8 + j][n] * BSCALE_);
      size_t dst = (size_t)e * DIN_ * DOUT_ + (size_t)(nt*64 + n) * DIN_ + kt*64 + ch*8;
      *(f16x8*)(Bh + dst) = h;
    }
  } else {
    int r = blockIdx.x - E_*32*32;      // sorted row
    int tok = perm[r];
    const float4* src = (const float4*)(tokens + (size_t)tok * DIN_);
    float4 x0 = src[tid*2], x1 = src[tid*2+1];
    float xs[8] = {x0.x, x0.y, x0.z, x0.w, x1.x, x1.y, x1.z, x1.w};
    f16x8 h, l;
#pragma unroll
    for (int j = 0; j < 8; j++) {
      float x = xs[j] * ASCALE_;
      _Float16 hi = (_Float16)x;
      h[j] = hi;
      l[j] = (_Float16)(x - (float)hi);
    }
    *(f16x8*)(Ah + (size_t)r * DIN_ + tid*8) = h;
    *(f16x8*)(Al + (size_t)r * DIN_ + tid*8) = l;
  }
}

// ---------- main grouped GEMM: 128x128x32, 4 waves (2x2), 4x4 frags/wave ----------
// 2-phase double-buffered pipeline (T3-min): stage tile k+1 while computing
// tile k; ONE __syncthreads per K-step. LDS 2 x 24KB (48KB -> 3 blocks/CU).
// Per buffer: [Ah 8K][Al 8K][Bh 8K], all [128 rows][32 k] f16,
// XOR-swizzled: 16B slot c stored at c ^ ((row>>1)&3).
// Grid 1D (1152 = 8 XCDs * 144), bijective XCD swizzle: XCD x owns n-columns
// {2x,2x+1} in 2(mt)x2(nt) supertiles -> B-panels ~9 L2-resident reuses.
__global__ __launch_bounds__(256) void k_moe_gemm(
    const _Float16* __restrict__ Ah, const _Float16* __restrict__ Al,
    const _Float16* __restrict__ Bh,
    const int* __restrict__ tiles, const int* __restrict__ ntl,
    const int* __restrict__ perm, float* __restrict__ out) {
  __shared__ char lds[49152];
  int lin = blockIdx.x;               // dispatch order; XCD = lin & 7 (heuristic)
  int xcd = lin & 7;
  int j   = lin >> 3;                 // 0..143 within this XCD
  int mt  = (j >> 2) * 2 + (j & 1);   // 0..71
  int nt  = xcd * 2 + ((j >> 1) & 1); // 0..15, fixed pair per XCD
  if (mt >= *ntl) return;
  int e = tiles[mt*3+0], row_start = tiles[mt*3+1], row_end = tiles[mt*3+2];
  int tid = threadIdx.x, lane = tid & 63, wave = tid >> 6;
  int wr = wave >> 1, wn = wave & 1;        // 2x2 wave grid, 64x64 per wave
  int n0 = nt * BN_;

  // per-thread global source pointers for the 6 staging calls (k advances by BK_)
  // chunks: 0,1 = Ah ; 2,3 = Al ; 4,5 = Bh
  const _Float16* gsrc[6];
#pragma unroll
  for (int c = 0; c < 6; c++) {
    int tilei = c >> 1;
    int q   = ((c & 1) << 12) + tid * 16;   // byte pos within 8 KiB tile
    int row = q >> 6;                        // 64 B per row
    int slot = (q >> 4) & 3;
    int sg = slot ^ ((row >> 1) & 3);        // pre-swizzled source slot
    if (tilei < 2) {
      int rg = row_start + row; if (rg > T_ - 1) rg = T_ - 1;   // clamp pad rows
      const _Float16* base = (tilei == 0) ? Ah : Al;
      gsrc[c] = base + (size_t)rg * DIN_ + sg * 8;
    } else {
      int ng = n0 + row;
      gsrc[c] = Bh + (size_t)e * DIN_ * DOUT_ + (size_t)ng * DIN_ + sg * 8;
    }
  }

  // hoisted swizzled LDS read offsets (constant over K)
  int rsel = lane & 15, ksel = lane >> 4;
  int aoff[4], boff[4];
#pragma unroll
  for (int m = 0; m < 4; m++) {
    int row = wr*64 + m*16 + rsel;
    aoff[m] = row*64 + ((ksel ^ ((row >> 1) & 3)) << 4);
  }
#pragma unroll
  for (int n = 0; n < 4; n++) {
    int row = wn*64 + n*16 + rsel;
    boff[n] = row*64 + ((ksel ^ ((row >> 1) & 3)) << 4);
  }

  // prologue: stage K-step 0 into buffer 0
#pragma unroll
  for (int c = 0; c < 6; c++) {
    gload_lds16(gsrc[c], lds + c*4096 + wave*1024);
    gsrc[c] += BK_;
  }
  __syncthreads();

  f32x4 acc[4][4] = {};
  int cur = 0;
  for (int k = 0; k < KSTEPS_; k++) {
    // stage next K-step into the other buffer (overlaps with compute below)
    if (k + 1 < KSTEPS_) {
      int nb = (cur ^ 1) * 24576;
#pragma unroll
      for (int c = 0; c < 6; c++) {
        gload_lds16(gsrc[c], lds + nb + c*4096 + wave*1024);
        gsrc[c] += BK_;
      }
    }

    const char* buf = lds + cur * 24576;
    f16x8 a_h[4], a_l[4], b_h[4];
#pragma unroll
    for (int m = 0; m < 4; m++) {
      a_h[m] = *(const f16x8*)(buf +         aoff[m]);
      a_l[m] = *(const f16x8*)(buf +  8192 + aoff[m]);
    }
#pragma unroll
    for (int n = 0; n < 4; n++)
      b_h[n] = *(const f16x8*)(buf + 16384 + boff[n]);
    __builtin_amdgcn_s_setprio(1);
#pragma unroll
    for (int m = 0; m < 4; m++)
#pragma unroll
      for (int n = 0; n < 4; n++) {
        acc[m][n] = __builtin_amdgcn_mfma_f32_16x16x32_f16(a_h[m], b_h[n], acc[m][n], 0, 0, 0);
        acc[m][n] = __builtin_amdgcn_mfma_f32_16x16x32_f16(a_l[m], b_h[n], acc[m][n], 0, 0, 0);
      }
    __builtin_amdgcn_s_setprio(0);
    // one barrier per K-step: drains vmcnt (prefetch landed in buf^1) and
    // lgkmcnt (our ds_reads of buf done before it's overwritten next iter)
    __syncthreads();
    cur ^= 1;
  }

  // epilogue: C/D layout col=lane&15, row=(lane>>4)*4+reg  [m89-verified]
  int colsel = lane & 15, rq = lane >> 4;
#pragma unroll
  for (int m = 0; m < 4; m++) {
#pragma unroll
    for (int r = 0; r < 4; r++) {
      int srow = row_start + wr*64 + m*16 + rq*4 + r;
      if (srow < row_end) {
        int tok = perm[srow];
        float* orow = out + (size_t)tok * DOUT_ + n0 + wn*64 + colsel;
#pragma unroll
        for (int n = 0; n < 4; n++) orow[n*16] = acc[m][n][r] * OSCALE_;
      }
    }
  }
}

// ---------- slow-but-correct fallback if ws is too small ----------
__global__ void k_naive(const float* __restrict__ tokens, const float* __restrict__ W,
                        const int* __restrict__ ids, float* __restrict__ out) {
  int t = blockIdx.x;
  int col = blockIdx.y * 256 + threadIdx.x;
  int e = ids[t];
  const float* a = tokens + (size_t)t * DIN_;
  const float* w = W + (size_t)e * DIN_ * DOUT_ + col;
  float s = 0.f;
  for (int k = 0; k < DIN_; k++) s += a[k] * w[(size_t)k * DOUT_];
  out[(size_t)t * DOUT_ + col] = s;
}

extern "C" void kernel_launch(void* const* d_in, const int* in_sizes, int n_in,
                              void* d_out, int out_size, void* d_ws, size_t ws_size,
                              hipStream_t stream) {
  const float* tokens = (const float*)d_in[0];
  const float* weight = (const float*)d_in[1];
  const int*   ids    = (const int*)d_in[2];
  float* out = (float*)d_out;
  char*  ws  = (char*)d_ws;

  if (ws_size < WS_END) {   // constant across calls -> graph-safe
    k_naive<<<dim3(T_, DOUT_/256), 256, 0, stream>>>(tokens, weight, ids, out);
    return;
  }

  int* ntl    = (int*)(ws + WS_NTILES);
  int* tiles  = (int*)(ws + WS_TILES);
  int* perm   = (int*)(ws + WS_PERM);
  _Float16* Ah = (_Float16*)(ws + WS_AH);
  _Float16* Al = (_Float16*)(ws + WS_AL);
  _Float16* Bh = (_Float16*)(ws + WS_BH);

  k_route<<<1, 1024, 0, stream>>>(ids, ntl, tiles, perm);
  k_conv<<<2*E_*32*32, 256, 0, stream>>>(weight, tokens, perm, Ah, Al, Bh);
  k_moe_gemm<<<MT_MAX_*NT_, 256, 0, stream>>>(Ah, Al, Bh, tiles, ntl, perm, out);
}